// Round 8
// baseline (471.534 us; speedup 1.0000x reference)
//
#include <hip/hip_runtime.h>
#include <hip/hip_cooperative_groups.h>
#include <math.h>

namespace cg = cooperative_groups;

#define NPTS 32768
#define G    20
#define NC   (G*G*G)            // 8000 cells per cloud
#define INVH 18.18181818f       // G / 1.1 (domain [0,1.1] covers target and output)
#define H    0.0548f            // conservative < true cell width 0.055: bound stays exact
#define CAP  40                 // slots per cell (lambda~5.4; P(overflow)~1e-20; list backs it up)
#define OCAP 4096               // overflow list capacity per cloud
#define NTHR 256
#define NQ   (2 * NPTS)         // 65536 queries (both directions)
#define MAXBLK 1024

// Same cell mapping EVERYWHERE (build + query) -> exactness argument holds.
__device__ __forceinline__ int cell1(float v) {
    int c = (int)(v * INVH);
    c = c < 0 ? 0 : c;
    return c > (G - 1) ? (G - 1) : c;
}

// min-dist over one cell's slot range (2-way ILP)
__device__ __forceinline__ float scan_cell(const float4* __restrict__ S, int base, int n,
                                           float qx, float qy, float qz, float mn) {
    int k = 0;
    for (; k + 2 <= n; k += 2) {
        float4 p0 = S[base + k], p1 = S[base + k + 1];
        float dx0 = qx - p0.x, dy0 = qy - p0.y, dz0 = qz - p0.z;
        float dx1 = qx - p1.x, dy1 = qy - p1.y, dz1 = qz - p1.z;
        float d0 = fmaf(dz0, dz0, fmaf(dy0, dy0, dx0 * dx0));
        float d1 = fmaf(dz1, dz1, fmaf(dy1, dy1, dx1 * dx1));
        mn = fminf(fminf(mn, d0), d1);
    }
    if (k < n) {
        float4 p0 = S[base + k];
        float dx0 = qx - p0.x, dy0 = qy - p0.y, dz0 = qz - p0.z;
        mn = fminf(mn, fmaf(dz0, dz0, fmaf(dy0, dy0, dx0 * dx0)));
    }
    return mn;
}

// 16-lane-group exact NN: lanes 0..8 scan the 3x3x3 (z,y)-rows in parallel,
// shfl_xor(16) reduce; rare exact shell fallback. Returns best (all 16 lanes).
__device__ float query_best(int gq, int r,
                            const float* __restrict__ target,
                            const float* __restrict__ outp,
                            const float4* __restrict__ slotsT,
                            const float4* __restrict__ slotsO,
                            const int* __restrict__ cnt,
                            const float4* __restrict__ ovT,
                            const float4* __restrict__ ovO,
                            int oCntT, int oCntO)
{
    const int dir = gq >> 15, qi = gq & (NPTS - 1);
    const float*  A    = dir ? outp : target;     // queries from original arrays
    const float4* SB   = dir ? slotsT : slotsO;   // candidates: other cloud
    const int*    cntB = cnt + (dir ^ 1) * NC;
    const float4* ovB  = dir ? ovT : ovO;
    const int     oB   = dir ? oCntT : oCntO;

    const float qx = A[3 * qi], qy = A[3 * qi + 1], qz = A[3 * qi + 2];
    const int cx = cell1(qx), cy = cell1(qy), cz = cell1(qz);

    float best = 3.4e38f;

    if (oB > 0) {                                  // candidates that missed the grid
        const int oe = oB < OCAP ? oB : OCAP;
        for (int k = r; k < oe; k += 16) {
            float4 p = ovB[k];
            float dx = qx - p.x, dy = qy - p.y, dz = qz - p.z;
            best = fminf(best, fmaf(dz, dz, fmaf(dy, dy, dx * dx)));
        }
    }

    if (r < 9) {                                   // 3x3x3: one (z,y) row per lane
        const int zz = cz + r / 3 - 1;
        const int yy = cy + r % 3 - 1;
        if (zz >= 0 && zz < G && yy >= 0 && yy < G) {
            const int xl = cx > 0 ? cx - 1 : 0;
            const int xh = cx < G - 1 ? cx + 1 : G - 1;
            const int base = (zz * G + yy) * G + xl;
            const int nx = xh - xl;                // 1 or 2
            int n0 = cntB[base];                   // issue counts together (MLP)
            int n1 = nx > 0 ? cntB[base + 1] : 0;
            int n2 = nx > 1 ? cntB[base + 2] : 0;
            n0 = n0 < CAP ? n0 : CAP; n1 = n1 < CAP ? n1 : CAP; n2 = n2 < CAP ? n2 : CAP;
            best = scan_cell(SB, base * CAP, n0, qx, qy, qz, best);
            best = scan_cell(SB, (base + 1) * CAP, n1, qx, qy, qz, best);
            best = scan_cell(SB, (base + 2) * CAP, n2, qx, qy, qz, best);
        }
    }
    #pragma unroll
    for (int off = 8; off; off >>= 1) best = fminf(best, __shfl_xor(best, off, 16));

    if (best > H * H) {                            // rare: expand shells, still exact
        for (int R = 2; R < G; ++R) {
            float smin = 3.4e38f;
            const int W = 2 * R + 1;
            for (int idx = r; idx < W * W; idx += 16) {
                const int dz = idx / W - R, dy = idx % W - R;
                const int zz = cz + dz, yy = cy + dy;
                if (zz < 0 || zz >= G || yy < 0 || yy >= G) continue;
                const int base = (zz * G + yy) * G;
                const int adz = dz < 0 ? -dz : dz, ady = dy < 0 ? -dy : dy;
                if ((adz > ady ? adz : ady) == R) {            // perimeter row
                    const int xl = cx - R < 0 ? 0 : cx - R;
                    const int xh = cx + R > G - 1 ? G - 1 : cx + R;
                    for (int xx = xl; xx <= xh; ++xx) {
                        const int cid = base + xx;
                        int n = cntB[cid]; n = n < CAP ? n : CAP;
                        smin = scan_cell(SB, cid * CAP, n, qx, qy, qz, smin);
                    }
                } else {                                       // interior: 2 edge cells
                    if (cx - R >= 0) {
                        const int cid = base + cx - R;
                        int n = cntB[cid]; n = n < CAP ? n : CAP;
                        smin = scan_cell(SB, cid * CAP, n, qx, qy, qz, smin);
                    }
                    if (cx + R <= G - 1) {
                        const int cid = base + cx + R;
                        int n = cntB[cid]; n = n < CAP ? n : CAP;
                        smin = scan_cell(SB, cid * CAP, n, qx, qy, qz, smin);
                    }
                }
            }
            #pragma unroll
            for (int off = 8; off; off >>= 1) smin = fminf(smin, __shfl_xor(smin, off, 16));
            best = fminf(best, smin);
            const float rh = (float)R * H;
            if (best <= rh * rh) break;            // unsearched provably > R*H away
        }
    }
    return best;
}

// ---------------------------------------------------------------------------
// Cooperative fused kernel — grid-size agnostic (any legal nblk is correct).
// ---------------------------------------------------------------------------
__global__ __launch_bounds__(NTHR, 2) void chamfer_fused(
    const float* __restrict__ target,
    const float* __restrict__ outp,
    const int* __restrict__ curp,
    float* __restrict__ out,
    void* __restrict__ wsv)
{
    float4* slotsT = (float4*)wsv;            // [NC*CAP]
    float4* slotsO = slotsT + NC * CAP;       // [NC*CAP]
    float4* ovT    = slotsO + NC * CAP;       // [OCAP]
    float4* ovO    = ovT + OCAP;              // [OCAP]
    int*    cnt    = (int*)(ovO + OCAP);      // [2*NC] + oCnt[2] appended
    int*    oCnt   = cnt + 2 * NC;
    float*  bsums  = (float*)(oCnt + 2);      // [<= MAXBLK]

    cg::grid_group grid = cg::this_grid();
    const int nthreads = gridDim.x * NTHR;
    const int tid = blockIdx.x * NTHR + threadIdx.x;

    // ---- P0: zero counters (grid-stride) ----
    for (int i = tid; i < 2 * NC + 2; i += nthreads) cnt[i] = 0;
    grid.sync();

    // ---- P1: build — claim slot via atomic, store point ----
    for (int i = tid; i < NQ; i += nthreads) {
        const int cloud = i >> 15, pi = i & (NPTS - 1);
        const float* P = cloud ? outp : target;
        const float x = P[3 * pi], y = P[3 * pi + 1], z = P[3 * pi + 2];
        const int cid = (cell1(z) * G + cell1(y)) * G + cell1(x);
        const int pos = atomicAdd(&cnt[cloud * NC + cid], 1);
        if (pos < CAP) {
            (cloud ? slotsO : slotsT)[cid * CAP + pos] = make_float4(x, y, z, 0.0f);
        } else {
            const int op = atomicAdd(&oCnt[cloud], 1);
            if (op < OCAP) (cloud ? ovO : ovT)[op] = make_float4(x, y, z, 0.0f);
        }
    }
    grid.sync();

    // ---- P2: query (16 lanes/query, grid-stride over groups) ----
    const int g0 = tid >> 4;
    const int r  = tid & 15;
    const int ngroups = nthreads >> 4;
    const int oT = oCnt[0], oO = oCnt[1];
    float acc = 0.0f;
    for (int gq = g0; gq < NQ; gq += ngroups) {
        const float best = query_best(gq, r, target, outp, slotsT, slotsO, cnt, ovT, ovO, oT, oO);
        if (r == 0) acc += sqrtf(best);
    }

    __shared__ float red[NTHR / 16];
    if (r == 0) red[threadIdx.x >> 4] = acc;
    __syncthreads();
    if (threadIdx.x == 0) {
        float s = 0.0f;
        #pragma unroll
        for (int i = 0; i < NTHR / 16; ++i) s += red[i];
        bsums[blockIdx.x] = s;
    }
    grid.sync();

    // ---- P3: finalize (block 0) ----
    if (blockIdx.x == 0) {
        float s = 0.0f;
        for (int i = threadIdx.x; i < (int)gridDim.x; i += NTHR) s += bsums[i];
        __shared__ float red2[NTHR];
        red2[threadIdx.x] = s;
        __syncthreads();
        #pragma unroll
        for (int off = NTHR / 2; off > 0; off >>= 1) {
            if (threadIdx.x < off) red2[threadIdx.x] += red2[threadIdx.x + off];
            __syncthreads();
        }
        if (threadIdx.x == 0) {
            const float decay = powf(1.02f, (float)(curp[0] / 20));
            out[0] = red2[0] / (float)NQ * 10.0f / decay;
        }
    }
}

// ---------------------------------------------------------------------------
// Fallback pipeline (used only if the cooperative launch is not possible).
// ---------------------------------------------------------------------------
__global__ __launch_bounds__(NTHR) void build_kernel(
    const float* __restrict__ target, const float* __restrict__ outp,
    float4* __restrict__ slotsT, float4* __restrict__ slotsO,
    float4* __restrict__ ovT, float4* __restrict__ ovO,
    int* __restrict__ cnt, int* __restrict__ oCnt)
{
    const int i = blockIdx.x * NTHR + threadIdx.x;   // grid = NQ/NTHR blocks
    const int cloud = i >> 15, pi = i & (NPTS - 1);
    const float* P = cloud ? outp : target;
    const float x = P[3 * pi], y = P[3 * pi + 1], z = P[3 * pi + 2];
    const int cid = (cell1(z) * G + cell1(y)) * G + cell1(x);
    const int pos = atomicAdd(&cnt[cloud * NC + cid], 1);
    if (pos < CAP) {
        (cloud ? slotsO : slotsT)[cid * CAP + pos] = make_float4(x, y, z, 0.0f);
    } else {
        const int op = atomicAdd(&oCnt[cloud], 1);
        if (op < OCAP) (cloud ? ovO : ovT)[op] = make_float4(x, y, z, 0.0f);
    }
}

__global__ __launch_bounds__(NTHR) void query_kernel(
    const float* __restrict__ target, const float* __restrict__ outp,
    const float4* __restrict__ slotsT, const float4* __restrict__ slotsO,
    const int* __restrict__ cnt, const float4* __restrict__ ovT,
    const float4* __restrict__ ovO, const int* __restrict__ oCnt,
    float* __restrict__ bsums)
{
    const int tid = blockIdx.x * NTHR + threadIdx.x;  // 4096 blocks: 1 query/group
    const int gq = tid >> 4, r = tid & 15;
    const float best = query_best(gq, r, target, outp, slotsT, slotsO, cnt,
                                  ovT, ovO, oCnt[0], oCnt[1]);
    __shared__ float red[NTHR / 16];
    if (r == 0) red[threadIdx.x >> 4] = sqrtf(best);
    __syncthreads();
    if (threadIdx.x == 0) {
        float s = 0.0f;
        #pragma unroll
        for (int i = 0; i < NTHR / 16; ++i) s += red[i];
        bsums[blockIdx.x] = s;
    }
}

__global__ __launch_bounds__(NTHR) void finalize_kernel(
    const float* __restrict__ bsums, const int* __restrict__ curp,
    float* __restrict__ out)
{
    float s = 0.0f;
    for (int i = threadIdx.x; i < 4096; i += NTHR) s += bsums[i];
    __shared__ float red2[NTHR];
    red2[threadIdx.x] = s;
    __syncthreads();
    #pragma unroll
    for (int off = NTHR / 2; off > 0; off >>= 1) {
        if (threadIdx.x < off) red2[threadIdx.x] += red2[threadIdx.x + off];
        __syncthreads();
    }
    if (threadIdx.x == 0) {
        const float decay = powf(1.02f, (float)(curp[0] / 20));
        out[0] = red2[0] / (float)NQ * 10.0f / decay;
    }
}

// ---------------------------------------------------------------------------
extern "C" void kernel_launch(void* const* d_in, const int* in_sizes, int n_in,
                              void* d_out, int out_size, void* d_ws, size_t ws_size,
                              hipStream_t stream) {
    const float* target = (const float*)d_in[0];
    const float* outp   = (const float*)d_in[1];
    const int*   cur    = (const int*)d_in[2];
    float*       out    = (float*)d_out;

    float4* slotsT = (float4*)d_ws;
    float4* slotsO = slotsT + NC * CAP;
    float4* ovT    = slotsO + NC * CAP;
    float4* ovO    = ovT + OCAP;
    int*    cnt    = (int*)(ovO + OCAP);
    int*    oCnt   = cnt + 2 * NC;
    float*  bsums  = (float*)(oCnt + 2);

    // Legal cooperative grid size, computed every call (deterministic).
    int occ = 0, cus = 0, dev = 0;
    (void)hipGetDevice(&dev);
    hipError_t eo = hipOccupancyMaxActiveBlocksPerMultiprocessor(
        &occ, (const void*)chamfer_fused, NTHR, 0);
    (void)hipDeviceGetAttribute(&cus, hipDeviceAttributeMultiprocessorCount, dev);
    long nblk = (eo == hipSuccess && cus > 0) ? (long)occ * (long)cus : 0;
    if (nblk > MAXBLK) nblk = MAXBLK;

    if (nblk >= 64) {
        void* vt = (void*)target; void* vo = (void*)outp; void* vc = (void*)cur;
        void* args[] = {(void*)&vt, (void*)&vo, (void*)&vc, (void*)&out, (void*)&d_ws};
        hipError_t le = hipLaunchCooperativeKernel((const void*)chamfer_fused,
                                                   dim3((unsigned)nblk), dim3(NTHR),
                                                   args, 0, stream);
        if (le == hipSuccess) return;
    }

    // Fallback: 4-node pipeline (proven structure).
    hipMemsetAsync(cnt, 0, (2 * NC + 2) * sizeof(int), stream);
    build_kernel<<<NQ / NTHR, NTHR, 0, stream>>>(target, outp, slotsT, slotsO,
                                                 ovT, ovO, cnt, oCnt);
    query_kernel<<<4096, NTHR, 0, stream>>>(target, outp, slotsT, slotsO, cnt,
                                            ovT, ovO, oCnt, bsums);
    finalize_kernel<<<1, NTHR, 0, stream>>>(bsums, cur, out);
}

// Round 11
// 153.485 us; speedup vs baseline: 3.0722x; 3.0722x over previous
//
#include <hip/hip_runtime.h>
#include <math.h>

#define NPTS 32768
#define G    20
#define NC   (G*G*G)            // 8000 cells per cloud
#define INVH 18.18181818f       // G / 1.1 (domain [0,1.1] covers target and output)
#define H    0.0548f            // conservative < true cell width 0.055: bound stays exact
#define CAP  40                 // slots per cell (lambda~5.4; overflow list backs it up)
#define OCAP 4096               // overflow list capacity per cloud
#define NTHR 256
#define NQ   (2 * NPTS)         // 65536 queries total
#define NTASK (2 * NC + 2)      // 16002 cell-tasks (+2 overflow query tasks)
#define QBLKS ((NTASK * 16 + NTHR - 1) / NTHR)   // 1001 blocks

// Same cell mapping EVERYWHERE (build + query) -> exactness argument holds.
__device__ __forceinline__ int cell1(float v) {
    int c = (int)(v * INVH);
    c = c < 0 ? 0 : c;
    return c > (G - 1) ? (G - 1) : c;
}

// min-dist over one cell's slot range (2-way ILP)
__device__ __forceinline__ float scan_cell(const float4* __restrict__ S, int base, int n,
                                           float qx, float qy, float qz, float mn) {
    int k = 0;
    for (; k + 2 <= n; k += 2) {
        float4 p0 = S[base + k], p1 = S[base + k + 1];
        float dx0 = qx - p0.x, dy0 = qy - p0.y, dz0 = qz - p0.z;
        float dx1 = qx - p1.x, dy1 = qy - p1.y, dz1 = qz - p1.z;
        float d0 = fmaf(dz0, dz0, fmaf(dy0, dy0, dx0 * dx0));
        float d1 = fmaf(dz1, dz1, fmaf(dy1, dy1, dx1 * dx1));
        mn = fminf(fminf(mn, d0), d1);
    }
    if (k < n) {
        float4 p0 = S[base + k];
        float dx0 = qx - p0.x, dy0 = qy - p0.y, dz0 = qz - p0.z;
        mn = fminf(mn, fmaf(dz0, dz0, fmaf(dy0, dy0, dx0 * dx0)));
    }
    return mn;
}

// 16-lane-group exact NN for one query point (math identical to round 8, which
// passed): lanes 0..8 scan the 3x3x3 (z,y)-rows in parallel, shfl_xor(16)
// reduce, rare exact shell fallback. Returns best on all 16 lanes.
__device__ __forceinline__ float nn_best(float qx, float qy, float qz, int r,
                                         const float4* __restrict__ SB,
                                         const int* __restrict__ cntB,
                                         const float4* __restrict__ ovB, int oB)
{
    const int cx = cell1(qx), cy = cell1(qy), cz = cell1(qz);
    float best = 3.4e38f;

    if (oB > 0) {                                  // candidates that missed the grid
        const int oe = oB < OCAP ? oB : OCAP;
        for (int k = r; k < oe; k += 16) {
            float4 p = ovB[k];
            float dx = qx - p.x, dy = qy - p.y, dz = qz - p.z;
            best = fminf(best, fmaf(dz, dz, fmaf(dy, dy, dx * dx)));
        }
    }

    if (r < 9) {                                   // 3x3x3: one (z,y) row per lane
        const int zz = cz + r / 3 - 1;
        const int yy = cy + r % 3 - 1;
        if (zz >= 0 && zz < G && yy >= 0 && yy < G) {
            const int xl = cx > 0 ? cx - 1 : 0;
            const int xh = cx < G - 1 ? cx + 1 : G - 1;
            const int base = (zz * G + yy) * G + xl;
            const int nx = xh - xl;                // 1 or 2
            int n0 = cntB[base];                   // issue counts together (MLP)
            int n1 = nx > 0 ? cntB[base + 1] : 0;
            int n2 = nx > 1 ? cntB[base + 2] : 0;
            n0 = n0 < CAP ? n0 : CAP; n1 = n1 < CAP ? n1 : CAP; n2 = n2 < CAP ? n2 : CAP;
            best = scan_cell(SB, base * CAP, n0, qx, qy, qz, best);
            best = scan_cell(SB, (base + 1) * CAP, n1, qx, qy, qz, best);
            best = scan_cell(SB, (base + 2) * CAP, n2, qx, qy, qz, best);
        }
    }
    #pragma unroll
    for (int off = 8; off; off >>= 1) best = fminf(best, __shfl_xor(best, off, 16));

    if (best > H * H) {                            // rare: expand shells, still exact
        for (int R = 2; R < G; ++R) {
            float smin = 3.4e38f;
            const int W = 2 * R + 1;
            for (int idx = r; idx < W * W; idx += 16) {
                const int dz = idx / W - R, dy = idx % W - R;
                const int zz = cz + dz, yy = cy + dy;
                if (zz < 0 || zz >= G || yy < 0 || yy >= G) continue;
                const int base = (zz * G + yy) * G;
                const int adz = dz < 0 ? -dz : dz, ady = dy < 0 ? -dy : dy;
                if ((adz > ady ? adz : ady) == R) {            // perimeter row
                    const int xl = cx - R < 0 ? 0 : cx - R;
                    const int xh = cx + R > G - 1 ? G - 1 : cx + R;
                    for (int xx = xl; xx <= xh; ++xx) {
                        const int cid = base + xx;
                        int n = cntB[cid]; n = n < CAP ? n : CAP;
                        smin = scan_cell(SB, cid * CAP, n, qx, qy, qz, smin);
                    }
                } else {                                       // interior: 2 edge cells
                    if (cx - R >= 0) {
                        const int cid = base + cx - R;
                        int n = cntB[cid]; n = n < CAP ? n : CAP;
                        smin = scan_cell(SB, cid * CAP, n, qx, qy, qz, smin);
                    }
                    if (cx + R <= G - 1) {
                        const int cid = base + cx + R;
                        int n = cntB[cid]; n = n < CAP ? n : CAP;
                        smin = scan_cell(SB, cid * CAP, n, qx, qy, qz, smin);
                    }
                }
            }
            #pragma unroll
            for (int off = 8; off; off >>= 1) smin = fminf(smin, __shfl_xor(smin, off, 16));
            best = fminf(best, smin);
            const float rh = (float)R * H;
            if (best <= rh * rh) break;            // unsearched provably > R*H away
        }
    }
    return best;
}

// ---------------------------------------------------------------------------
// Build: atomic slot claim, no scan/cursor. (Validated in round 8.)
// ---------------------------------------------------------------------------
__global__ __launch_bounds__(NTHR) void build_kernel(
    const float* __restrict__ target, const float* __restrict__ outp,
    float4* __restrict__ slotsT, float4* __restrict__ slotsO,
    float4* __restrict__ ovT, float4* __restrict__ ovO,
    int* __restrict__ cnt, int* __restrict__ oCnt)
{
    const int i = blockIdx.x * NTHR + threadIdx.x;   // grid = NQ/NTHR = 256 blocks
    const int cloud = i >> 15, pi = i & (NPTS - 1);
    const float* P = cloud ? outp : target;
    const float x = P[3 * pi], y = P[3 * pi + 1], z = P[3 * pi + 2];
    const int cid = (cell1(z) * G + cell1(y)) * G + cell1(x);
    const int pos = atomicAdd(&cnt[cloud * NC + cid], 1);
    if (pos < CAP) {
        (cloud ? slotsO : slotsT)[cid * CAP + pos] = make_float4(x, y, z, 0.0f);
    } else {
        const int op = atomicAdd(&oCnt[cloud], 1);
        if (op < OCAP) (cloud ? ovO : ovT)[op] = make_float4(x, y, z, 0.0f);
    }
}

// ---------------------------------------------------------------------------
// Cell-centric query: one 16-lane group per cell-task; the group's queries are
// its own cell's slot points -> neighborhood lines loaded once, L1-hot for the
// remaining points. Last block (ticket) finalizes: strided sum + decay.
// ---------------------------------------------------------------------------
__global__ __launch_bounds__(NTHR) void query_kernel(
    const float4* __restrict__ slotsT, const float4* __restrict__ slotsO,
    const float4* __restrict__ ovT, const float4* __restrict__ ovO,
    const int* __restrict__ cnt, const int* __restrict__ oCnt,
    float* __restrict__ bsums, int* __restrict__ done,
    const int* __restrict__ curp, float* __restrict__ out)
{
    const int tid = blockIdx.x * NTHR + threadIdx.x;
    const int g = tid >> 4, r = tid & 15;
    const int oT = oCnt[0], oO = oCnt[1];

    float acc = 0.0f;
    if (g < NTASK) {
        int cloud, qn;
        const float4* Q;
        if (g < 2 * NC) {
            cloud = g >= NC;
            const int cid = g - cloud * NC;
            int n = cnt[g]; qn = n < CAP ? n : CAP;
            Q = (cloud ? slotsO : slotsT) + cid * CAP;
        } else {                                   // overflow-point queries (rare)
            cloud = g - 2 * NC;
            qn = cloud ? (oO < OCAP ? oO : OCAP) : (oT < OCAP ? oT : OCAP);
            Q = cloud ? ovO : ovT;
        }
        const float4* SB   = cloud ? slotsT : slotsO;   // candidates: other cloud
        const int*    cntB = cnt + (cloud ^ 1) * NC;
        const float4* ovB  = cloud ? ovT : ovO;
        const int     oB   = cloud ? oT : oO;

        for (int i = 0; i < qn; ++i) {             // same home cell -> hot lines
            const float4 q = Q[i];
            const float best = nn_best(q.x, q.y, q.z, r, SB, cntB, ovB, oB);
            if (r == 0) acc += sqrtf(best);
        }
    }

    // per-block deterministic sum of group results
    __shared__ float red[NTHR / 16];
    if (r == 0) red[threadIdx.x >> 4] = acc;
    __syncthreads();
    if (threadIdx.x == 0) {
        float s = 0.0f;
        #pragma unroll
        for (int i = 0; i < NTHR / 16; ++i) s += red[i];
        bsums[blockIdx.x] = s;
    }

    // last-block finalize (release/acquire ticket; order-independent)
    __shared__ int is_last;
    if (threadIdx.x == 0) {
        __threadfence();                           // release bsums[blockIdx.x]
        is_last = (atomicAdd(done, 1) == (int)gridDim.x - 1);
    }
    __syncthreads();
    if (is_last) {
        __threadfence();                           // acquire all bsums
        float s = 0.0f;
        for (int i = threadIdx.x; i < (int)gridDim.x; i += NTHR) s += bsums[i];
        __shared__ float red2[NTHR];
        red2[threadIdx.x] = s;
        __syncthreads();
        #pragma unroll
        for (int off = NTHR / 2; off > 0; off >>= 1) {
            if (threadIdx.x < off) red2[threadIdx.x] += red2[threadIdx.x + off];
            __syncthreads();
        }
        if (threadIdx.x == 0) {
            const float decay = powf(1.02f, (float)(curp[0] / 20));
            out[0] = red2[0] / (float)NQ * 10.0f / decay;
        }
    }
}

// ---------------------------------------------------------------------------
extern "C" void kernel_launch(void* const* d_in, const int* in_sizes, int n_in,
                              void* d_out, int out_size, void* d_ws, size_t ws_size,
                              hipStream_t stream) {
    const float* target = (const float*)d_in[0];
    const float* outp   = (const float*)d_in[1];
    const int*   cur    = (const int*)d_in[2];
    float*       out    = (float*)d_out;

    // ws layout (~10.4 MB): slotsT | slotsO | ovT | ovO | cnt | oCnt | done | bsums
    float4* slotsT = (float4*)d_ws;
    float4* slotsO = slotsT + NC * CAP;
    float4* ovT    = slotsO + NC * CAP;
    float4* ovO    = ovT + OCAP;
    int*    cnt    = (int*)(ovO + OCAP);      // [2*NC]
    int*    oCnt   = cnt + 2 * NC;            // [2]
    int*    done   = oCnt + 2;                // [1]
    float*  bsums  = (float*)(done + 1);      // [QBLKS]

    hipMemsetAsync(cnt, 0, (2 * NC + 3) * sizeof(int), stream);
    build_kernel<<<NQ / NTHR, NTHR, 0, stream>>>(target, outp, slotsT, slotsO,
                                                 ovT, ovO, cnt, oCnt);
    query_kernel<<<QBLKS, NTHR, 0, stream>>>(slotsT, slotsO, ovT, ovO, cnt, oCnt,
                                             bsums, done, cur, out);
}